// Round 1
// 126.640 us; speedup vs baseline: 1.0177x; 1.0177x over previous
//
#include <hip/hip_runtime.h>

// SNNLinear, exact-trajectory i8-digit MFMA. Round 19 = FUSED gemm+scan.
//   - A8 re-laid out b-major: row r = b*112 + t (t padded 100->112 so each
//     batch row is exactly 7 sixteen-row fragment tiles). Pad rows are zero.
//   - gemm_scan block = (b, ng): 112m x 64n x 1024k x 4 planes, 4 waves
//     (wave w owns n16-tile w: acc[7][4], 28 mfma/kt). LDS-staged,
//     double-buffered, reg-staging 1 barrier/kt (R18 pattern re-geometried:
//     23 KB/kt = 7 A-chunks + 16 B-chunks of 1 KB, wave w stages c=w+4j).
//   - epilogue: exact i64 Horner -> f64 du -> staged to LDS (100x64 f64 =
//     50 KB, overlays the staging dbuf after the last barrier), then wave 0
//     runs the 100-step f64 scan from LDS and writes ss/mem_out/hat_s
//     directly. Chi/Lo round-trip (78.6 MB HBM) and the 3rd kernel are gone.
// Math bit-compatible with R16/R18 scan except du is now EXACT f64 instead
// of hi-f32 + lo-f16*2^-12 reconstruction (a ~2^-35 relative perturbation of
// the passing trajectory; strictly closer to exact).
// Outputs: ss[100,64,1024] | mem_out[64,1024] | hat_s[64,1024]
// ws: [0, 7.34M) A8 (b-major, t-pad 112) ; [7.34M, 11.53M) Bt (4 planes)

typedef __attribute__((ext_vector_type(4))) int int4v;

#define T_STEPS 100
#define T_PAD   112
#define BO      65536
#define K_DIM   1024
#define A8_OFF  0
#define BT_OFF  7340032      // 64*112*1024
#define LDS_BUF 23552        // 7 KB A + 16 KB B per kt

// ---- prepass: spikes -> A8 (b-major, t-padded, fragment-tiled);
//               W -> Bt 4 balanced base-256 i8 planes (R16 verbatim path) ----
__global__ __launch_bounds__(256)
void prepass(const float* __restrict__ S, const float* __restrict__ W,
             signed char* __restrict__ A8, signed char* __restrict__ Bt) {
    const int wave = blockIdx.x * 4 + (threadIdx.x >> 6);  // 0..8191
    const int lane = threadIdx.x & 63;
    const int r16 = lane & 15, quad = lane >> 4;

    if (wave < 7168) {
        // A tile: wave = b*112 + jt*16 + k64 ; rows t = jt*16 + r16
        const int b   = wave / 112;
        const int rem = wave - b * 112;
        const int jt  = rem >> 4, k64 = rem & 15;
        const int t   = jt * 16 + r16;
        union { signed char c[16]; int4v v; } u;
        if (t < T_STEPS) {
            const float* sp = S + ((size_t)t * 64 + b) * K_DIM + k64 * 64 + quad * 16;
            const float4 s0 = *(const float4*)(sp);
            const float4 s1 = *(const float4*)(sp + 4);
            const float4 s2 = *(const float4*)(sp + 8);
            const float4 s3 = *(const float4*)(sp + 12);
            const float sv[16] = {s0.x,s0.y,s0.z,s0.w, s1.x,s1.y,s1.z,s1.w,
                                  s2.x,s2.y,s2.z,s2.w, s3.x,s3.y,s3.z,s3.w};
#pragma unroll
            for (int e = 0; e < 16; ++e) u.c[e] = (signed char)sv[e];  // exact 0/1
        } else {
#pragma unroll
            for (int e = 0; e < 16; ++e) u.c[e] = 0;                   // t-pad
        }
        *(int4v*)(A8 + (size_t)wave * 1024 + lane * 16) = u.v;
    } else {
        const int t2 = wave - 7168;                 // 0..1023
        const int n16 = t2 >> 4, k64 = t2 & 15;
        const int n = n16 * 16 + r16;
        const float* wp = W + (size_t)n * K_DIM + k64 * 64 + quad * 16;
        const float4 w0 = *(const float4*)(wp);
        const float4 w1 = *(const float4*)(wp + 4);
        const float4 w2 = *(const float4*)(wp + 8);
        const float4 w3 = *(const float4*)(wp + 12);
        const float wv[16] = {w0.x,w0.y,w0.z,w0.w, w1.x,w1.y,w1.z,w1.w,
                              w2.x,w2.y,w2.z,w2.w, w3.x,w3.y,w3.z,w3.w};
        union { signed char c[16]; int4v v; } u[4];
#pragma unroll
        for (int e = 0; e < 16; ++e) {
            long long q = llrint((double)wv[e] * 0x1p28);   // |q| < 2^31
#pragma unroll
            for (int p = 0; p < 3; ++p) {
                const int d = (int)(((q + 128) & 255) - 128);  // [-128,127]
                u[p].c[e] = (signed char)d;
                q = (q - d) >> 8;                              // exact
            }
            u[3].c[e] = (signed char)q;                        // |d3| <= ~88
        }
        signed char* base = Bt + (size_t)(n16 * 16 + k64) * 4 * 1024 + lane * 16;
#pragma unroll
        for (int p = 0; p < 4; ++p)
            *(int4v*)(base + (size_t)p * 1024) = u[p].v;
    }
}

// ---- fused GEMM + membrane scan. Block = (b, ng): 112m x 64n, 4 waves
// (wave w = n16-tile w). Reg-staged double-buffered LDS, 1 barrier/kt. ----
__global__ __launch_bounds__(256, 2)
void gemm_scan(const signed char* __restrict__ A8,
               const signed char* __restrict__ Bt,
               const float* __restrict__ bias,
               const float* __restrict__ mem0,
               float* __restrict__ out) {
    __shared__ int4v lds4[3200];                 // 51200 B: dbuf staging, then du
    signed char* slds = (signed char*)lds4;
    double* dulds = (double*)lds4;

    const int bid = blockIdx.x;                  // 0..1023
    const int b  = bid >> 4;                     // batch row
    const int ng = bid & 15;                     // 64-wide n-group

    const int tid = threadIdx.x;
    const int lane = tid & 63, wid = tid >> 6;
    const int quad = lane >> 4, r16 = lane & 15;

    // staging: wave w handles chunks c = w + 4j (c < 23).
    // c<7: A tile jt=c ; c>=7: B chunk j2=c-7 (n16loc=j2>>2, plane=j2&3)
    const signed char* sbase[6];
    int sstride[6], ldsoff[6];
#pragma unroll
    for (int j = 0; j < 6; ++j) {
        const int c = wid + 4 * j;
        const int cc = (c < 23) ? c : 0;         // dummy for wave3's j=5 (guarded below)
        if (cc < 7) {
            sbase[j] = A8 + ((size_t)(b * T_PAD + cc * 16)) * 1024 + lane * 16;
            sstride[j] = 1024;                   // +kt -> next k64 tile
            ldsoff[j] = cc * 1024 + lane * 16;
        } else {
            const int j2 = cc - 7;
            sbase[j] = Bt + ((size_t)((ng * 4 + (j2 >> 2)) * 16) * 4 + (j2 & 3)) * 1024
                          + lane * 16;
            sstride[j] = 4096;                   // +kt -> next k64 (4 planes apart)
            ldsoff[j] = 7168 + j2 * 1024 + lane * 16;
        }
    }
    // fragment read offsets (lane-linear -> conflict-free b128)
    int aoff[7], boff[4];
#pragma unroll
    for (int i = 0; i < 7; ++i) aoff[i] = i * 1024 + lane * 16;
#pragma unroll
    for (int p = 0; p < 4; ++p) boff[p] = 7168 + (wid * 4 + p) * 1024 + lane * 16;

    int4v sreg[6];
    int4v acc[7][4] = {};

    // prologue: stage kt=0 into buf0
#pragma unroll
    for (int j = 0; j < 6; ++j) if (wid + 4 * j < 23) sreg[j] = *(const int4v*)(sbase[j]);
#pragma unroll
    for (int j = 0; j < 6; ++j) if (wid + 4 * j < 23) *(int4v*)(slds + ldsoff[j]) = sreg[j];
    __syncthreads();

    for (int kt = 0; kt < 16; ++kt) {
        const int cur = (kt & 1) * LDS_BUF, nxt = LDS_BUF - cur;
        if (kt + 1 < 16) {                       // global loads in flight over MFMA
#pragma unroll
            for (int j = 0; j < 6; ++j) if (wid + 4 * j < 23)
                sreg[j] = *(const int4v*)(sbase[j] + (size_t)(kt + 1) * sstride[j]);
        }
        int4v af[7], bf[4];
#pragma unroll
        for (int i = 0; i < 7; ++i) af[i] = *(const int4v*)(slds + cur + aoff[i]);
#pragma unroll
        for (int p = 0; p < 4; ++p) bf[p] = *(const int4v*)(slds + cur + boff[p]);
#pragma unroll
        for (int p = 0; p < 4; ++p)
#pragma unroll
            for (int i = 0; i < 7; ++i)
                acc[i][p] = __builtin_amdgcn_mfma_i32_16x16x64_i8(
                    af[i], bf[p], acc[i][p], 0, 0, 0);
        if (kt + 1 < 16) {
#pragma unroll
            for (int j = 0; j < 6; ++j) if (wid + 4 * j < 23)
                *(int4v*)(slds + nxt + ldsoff[j]) = sreg[j];
        }
        __syncthreads();
    }
    // After the final barrier every wave's ds_reads are complete: the whole
    // 50 KB LDS is now free to hold du[t][n_loc] (f64, t<100 only).

    // exact i64 Horner -> f64 du -> LDS  (C layout: row = quad*4+e, col = r16)
    const int n_loc = wid * 16 + r16;
    const double bd = (double)bias[ng * 64 + n_loc];
#pragma unroll
    for (int i = 0; i < 7; ++i)
#pragma unroll
        for (int e = 0; e < 4; ++e) {
            const int t = i * 16 + quad * 4 + e;
            if (t < T_STEPS) {
                long long v = (long long)acc[i][3][e];
                v = v * 256 + (long long)acc[i][2][e];
                v = v * 256 + (long long)acc[i][1][e];
                v = v * 256 + (long long)acc[i][0][e];   // exact, |v| < 2^42
                dulds[t * 64 + n_loc] = (double)v * 0x1p-28 + bd;
            }
        }
    __syncthreads();

    // membrane scan (R16 math verbatim, du exact f64): wave 0, 64 columns.
    // waves 1-3 exit; no further barriers.
    if (wid == 0) {
        const int bo = b * 1024 + ng * 64 + lane;
        double m = (double)mem0[bo];
        double cnt = 0.0;
        double d[4];
#pragma unroll
        for (int u = 0; u < 4; ++u) d[u] = dulds[u * 64 + lane];
        for (int g = 0; g < 25; ++g) {
            double dn[4];
            if (g + 1 < 25) {
#pragma unroll
                for (int u = 0; u < 4; ++u) dn[u] = dulds[((g + 1) * 4 + u) * 64 + lane];
            }
#pragma unroll
            for (int u = 0; u < 4; ++u) {
                m += d[u];
                const double s = (m > 15.0) ? 1.0 : 0.0;
                m = fmin(fmax(m, 0.0), 15.0);
                out[(size_t)(g * 4 + u) * BO + bo] = (float)s;
                cnt += s;
                m -= m * s;
            }
            if (g + 1 < 25) {
#pragma unroll
                for (int u = 0; u < 4; ++u) d[u] = dn[u];
            }
        }
        out[(size_t)T_STEPS * BO + bo] = (float)m;
        out[(size_t)(T_STEPS + 1) * BO + bo] = (float)(cnt * 0.01);
    }
}

extern "C" void kernel_launch(void* const* d_in, const int* in_sizes, int n_in,
                              void* d_out, int out_size, void* d_ws, size_t ws_size,
                              hipStream_t stream) {
    const float* spikes = (const float*)d_in[0];  // [100,64,1024]
    const float* mem    = (const float*)d_in[1];  // [64,1024]
    // d_in[2] = hat_spikes: dead in forward
    const float* W      = (const float*)d_in[3];  // [1024,1024]
    const float* b      = (const float*)d_in[4];  // [1024]
    float* out = (float*)d_out;
    signed char* A8 = (signed char*)d_ws + A8_OFF;
    signed char* Bt = (signed char*)d_ws + BT_OFF;

    prepass<<<dim3(2048), 256, 0, stream>>>(spikes, W, A8, Bt);
    gemm_scan<<<dim3(1024), 256, 0, stream>>>(A8, Bt, b, mem, out);
}